// Round 2
// baseline (860.734 us; speedup 1.0000x reference)
//
#include <hip/hip_runtime.h>

#define NN 16384   // total nodes (4*64*64)
#define CC 48      // channels
// xg layout: per node, 52 floats = 48 features + [sq, 0, 0, 0]  (13 float4, 16B aligned)

// ---------- kernel 1: [B,C,H,W] -> xg[N][52] (features + squared-norm) ----------
__global__ __launch_bounds__(256) void prep_kernel(const float* __restrict__ x,
                                                   float* __restrict__ xg) {
  __shared__ float tile[48][65];   // +1 pad
  __shared__ float sqcol[64];
  int tid = threadIdx.x;
  int b   = blockIdx.x >> 6;          // batch image 0..3
  int hw0 = (blockIdx.x & 63) << 6;   // 64-wide hw tile
#pragma unroll
  for (int p = 0; p < 12; ++p) {
    int it = tid + p * 256;
    int r = it >> 6, col = it & 63;
    tile[r][col] = x[(b * 48 + r) * 4096 + hw0 + col];
  }
  __syncthreads();
  if (tid < 64) {
    float s = 0.f;
#pragma unroll
    for (int r = 0; r < 48; ++r) { float v = tile[r][tid]; s += v * v; }
    sqcol[tid] = s;
  }
  __syncthreads();
  float4* xg4 = (float4*)xg;
#pragma unroll
  for (int p = 0; p < 4; ++p) {
    int it = tid + p * 256;
    if (it < 832) {
      int col = it / 13;
      int q   = it - col * 13;
      float4 v;
      if (q < 12) {
        v.x = tile[q * 4 + 0][col]; v.y = tile[q * 4 + 1][col];
        v.z = tile[q * 4 + 2][col]; v.w = tile[q * 4 + 3][col];
      } else {
        v.x = sqcol[col]; v.y = 0.f; v.z = 0.f; v.w = 0.f;
      }
      xg4[(b * 4096 + hw0 + col) * 13 + q] = v;
    }
  }
}

// ---------- kernel 2: fused distance + top-9 ----------
// 512 blocks x 512 threads; block owns 32 query nodes i.
// wave w: g = w>>2 picks i-group (16 i), c = w&3 picks j-chunk; lanes: 16 i x 4 jl.
// thread stream: j = js + (c*4+jl) + 16*t  (256 candidates).
// top-9 as packed u64 keys: (sortable_fp32(dist) << 14) | j  -- single-compare
// insert AND exact (dist, lower-index-wins) tie-break semantics.
__global__ __launch_bounds__(512, 4) void knn_kernel(const float* __restrict__ xg,
                                                     int* __restrict__ nbr,
                                                     int* __restrict__ deg) {
  __shared__ unsigned long long L[16][32][9];
  int tid  = threadIdx.x;
  int w    = tid >> 6;
  int lane = tid & 63;
  int g  = w >> 2, c  = w & 3;
  int iw = lane >> 2, jl = lane & 3;
  int li = g * 16 + iw;
  int i  = blockIdx.x * 32 + li;
  int sub = c * 4 + jl;

  // batch id per torch.linspace(0,B,N).long(): floor(4*i/16383)
  int batch = (4 * i) / 16383;
  int js = batch * 4096;
  int je = js + 4096;
  if (batch >= 3) je = 16383;
  if (batch == 4) { js = 16383; je = 16384; }

  const float4* xg4 = (const float4*)xg;
  float4 xi[12];
#pragma unroll
  for (int q = 0; q < 12; ++q) xi[q] = xg4[(size_t)i * 13 + q];

  unsigned long long q9[9];
#pragma unroll
  for (int k = 0; k < 9; ++k) q9[k] = ~0ull;

  for (int j = js + sub; j < je; j += 16) {
    const float4* row = xg4 + (size_t)j * 13;
    float4 r[13];
#pragma unroll
    for (int q = 0; q < 13; ++q) r[q] = row[q];
    float ax = 0.f, ay = 0.f, az = 0.f, aw = 0.f;
#pragma unroll
    for (int q = 0; q < 12; ++q) {
      ax += r[q].x * xi[q].x;
      ay += r[q].y * xi[q].y;
      az += r[q].z * xi[q].z;
      aw += r[q].w * xi[q].w;
    }
    // ranking key: sq[j] - 2*dot (sq[i] per-row constant, dropped; order preserved)
    float dist = r[12].x - 2.0f * ((ax + ay) + (az + aw));
    unsigned k32 = __float_as_uint(dist);
    k32 = ((int)k32 >= 0) ? (k32 | 0x80000000u) : ~k32;  // sortable-uint map
    unsigned long long key = ((unsigned long long)k32 << 14) | (unsigned)j;
    if (key < q9[8]) {
      unsigned long long cu = key;
#pragma unroll
      for (int k = 0; k < 9; ++k) {
        bool lt = cu < q9[k];
        unsigned long long mn = lt ? cu : q9[k];
        cu    = lt ? q9[k] : cu;
        q9[k] = mn;
      }
    }
  }

#pragma unroll
  for (int k = 0; k < 9; ++k) L[sub][li][k] = q9[k];
  __syncthreads();

  if (tid < 32) {
    int im = blockIdx.x * 32 + tid;
    unsigned long long ptrs = 0;  // 16 x 4-bit head pointers
    int outi[9];
#pragma unroll
    for (int k = 0; k < 9; ++k) {
      unsigned long long bd = ~0ull; int bl = 0;
#pragma unroll
      for (int l = 0; l < 16; ++l) {
        int p = (int)((ptrs >> (4 * l)) & 15);
        unsigned long long v = L[l][tid][p];
        if (v < bd) { bd = v; bl = l; }
      }
      ptrs += 1ull << (4 * bl);
      outi[k] = (int)(bd & 0x3FFFull);
    }
    // node 16383 sits alone in "batch 4": top_k over one valid entry + (-inf) ties
    // -> neighbors {16383, 0,1,...,7} (lowest-index tie-break). Matters for deg[0..7].
    if (im == NN - 1) {
      outi[0] = NN - 1;
#pragma unroll
      for (int k = 1; k < 9; ++k) outi[k] = k - 1;
    }
#pragma unroll
    for (int k = 0; k < 9; ++k) {
      nbr[im * 9 + k] = outi[k];
      atomicAdd(&deg[outi[k]], 1);
    }
  }
}

// ---------- kernel 3: dinv ----------
__global__ __launch_bounds__(256) void dinv_kernel(const int* __restrict__ deg,
                                                   float* __restrict__ dinv) {
  int i = blockIdx.x * 256 + threadIdx.x;
  int d = deg[i];
  dinv[i] = d > 0 ? 1.0f / sqrtf((float)d) : 0.0f;
}

// ---------- kernel 4: tx1 gather + out = relu(xf@W0 + tx1@W1 + b) ----------
__global__ __launch_bounds__(256) void out_kernel(const float* __restrict__ xg,
                                                  const int* __restrict__ nbr,
                                                  const float* __restrict__ dinv,
                                                  const float* __restrict__ W0,
                                                  const float* __restrict__ W1,
                                                  const float* __restrict__ bias,
                                                  float* __restrict__ out) {
  __shared__ float w0s[48 * 48], w1s[48 * 48], bsh[48];
  __shared__ __align__(16) float xr[64 * 48];
  __shared__ float tx[64 * 48];
  __shared__ float wd[64][9];
  __shared__ int   jn[64][9];
  __shared__ float din[64];
  int tid = threadIdx.x;
  int r0  = blockIdx.x * 64;

  for (int p = tid; p < 2304; p += 256) { w0s[p] = W0[p]; w1s[p] = W1[p]; }
  if (tid < 48) bsh[tid] = bias[tid];
  if (tid < 64) din[tid] = dinv[r0 + tid];
  const float4* xg4 = (const float4*)xg;
  float4* xr4 = (float4*)xr;
  for (int p = tid; p < 768; p += 256) {
    int r = p / 12, q = p - r * 12;
    xr4[r * 12 + q] = xg4[(r0 + r) * 13 + q];
  }
  for (int p = tid; p < 576; p += 256) {
    int r = p / 9, k = p - r * 9;
    int j = nbr[(r0 + r) * 9 + k];
    jn[r][k] = j;
    wd[r][k] = dinv[j];
  }
  __syncthreads();

  // tx1 rows: tx1[i] = -dinv[i] * sum_k dinv[j_k] * xf[j_k]
  for (int p = tid; p < 3072; p += 256) {
    int r = p / 48, ch = p - r * 48;
    float s = 0.f;
#pragma unroll
    for (int k = 0; k < 9; ++k) s += wd[r][k] * xg[jn[r][k] * 52 + ch];
    tx[r * 48 + ch] = -din[r] * s;
  }
  __syncthreads();

  // out[r][o] = relu(b[o] + sum_c xr[r][c]*W0[c][o] + tx[r][c]*W1[c][o])
  for (int p = tid; p < 3072; p += 256) {
    int r = p / 48, o = p - r * 48;
    float acc = bsh[o];
#pragma unroll
    for (int cc = 0; cc < 48; ++cc)
      acc += xr[r * 48 + cc] * w0s[cc * 48 + o] + tx[r * 48 + cc] * w1s[cc * 48 + o];
    out[(r0 + r) * 48 + o] = fmaxf(acc, 0.f);
  }
}

extern "C" void kernel_launch(void* const* d_in, const int* in_sizes, int n_in,
                              void* d_out, int out_size, void* d_ws, size_t ws_size,
                              hipStream_t stream) {
  const float* x  = (const float*)d_in[0];
  const float* W0 = (const float*)d_in[1];
  const float* W1 = (const float*)d_in[2];
  const float* b  = (const float*)d_in[3];
  float* out = (float*)d_out;
  char* ws = (char*)d_ws;
  float* xg   = (float*)(ws);                 // 16384*52*4 = 3,407,872 B
  int*   nbr  = (int*)(ws + 3407872);         // 16384*9*4  =   589,824 B
  int*   deg  = (int*)(ws + 3997696);         //               65,536 B
  float* dinv = (float*)(ws + 4063232);       //               65,536 B

  hipMemsetAsync(deg, 0, NN * sizeof(int), stream);
  prep_kernel<<<256, 256, 0, stream>>>(x, xg);
  knn_kernel<<<512, 512, 0, stream>>>(xg, nbr, deg);
  dinv_kernel<<<64, 256, 0, stream>>>(deg, dinv);
  out_kernel<<<256, 256, 0, stream>>>(xg, nbr, dinv, W0, W1, b, out);
}

// Round 3
// 481.241 us; speedup vs baseline: 1.7886x; 1.7886x over previous
//
#include <hip/hip_runtime.h>

#define NN 16384   // total nodes (4*64*64)
#define CC 48      // channels
// xg layout: per node, 52 floats = 48 features + [sq, 0, 0, 0]  (13 float4, 16B aligned)

// ---------- kernel 1: [B,C,H,W] -> xg[N][52] (features + squared-norm) ----------
__global__ __launch_bounds__(256) void prep_kernel(const float* __restrict__ x,
                                                   float* __restrict__ xg) {
  __shared__ float tile[48][65];   // +1 pad
  __shared__ float sqcol[64];
  int tid = threadIdx.x;
  int b   = blockIdx.x >> 6;          // batch image 0..3
  int hw0 = (blockIdx.x & 63) << 6;   // 64-wide hw tile
#pragma unroll
  for (int p = 0; p < 12; ++p) {
    int it = tid + p * 256;
    int r = it >> 6, col = it & 63;
    tile[r][col] = x[(b * 48 + r) * 4096 + hw0 + col];
  }
  __syncthreads();
  if (tid < 64) {
    float s = 0.f;
#pragma unroll
    for (int r = 0; r < 48; ++r) { float v = tile[r][tid]; s += v * v; }
    sqcol[tid] = s;
  }
  __syncthreads();
  float4* xg4 = (float4*)xg;
#pragma unroll
  for (int p = 0; p < 4; ++p) {
    int it = tid + p * 256;
    if (it < 832) {
      int col = it / 13;
      int q   = it - col * 13;
      float4 v;
      if (q < 12) {
        v.x = tile[q * 4 + 0][col]; v.y = tile[q * 4 + 1][col];
        v.z = tile[q * 4 + 2][col]; v.w = tile[q * 4 + 3][col];
      } else {
        v.x = sqcol[col]; v.y = 0.f; v.z = 0.f; v.w = 0.f;
      }
      xg4[(b * 4096 + hw0 + col) * 13 + q] = v;
    }
  }
}

// ---------- kernel 2: fused distance + partial top-9 ----------
// One i PER LANE; the candidate row xg[j] is wave-uniform -> scalar (SMEM) loads
// through the constant cache, broadcast to all 64 lanes as the SGPR operand of
// v_fma_f32. Inner loop has ZERO per-lane VMEM.
// wave wid: ig = wid%256 picks 64 consecutive i; sp = wid/256 picks j-split
// (j = js+sp, step S). Partial sorted top-9 (u64 keys) to global; merged later.
// Batch boundaries are multiples of 64 except node 16383 (alone in "batch 4"):
// its lane computes garbage vs batch-3 candidates; merge_kernel overrides it.
__global__ __launch_bounds__(256, 4) void knn_kernel(const float* __restrict__ xg,
                                                     unsigned long long* __restrict__ part,
                                                     int S) {
  int tid  = threadIdx.x;
  int lane = tid & 63;
  int wid  = blockIdx.x * 4 + (tid >> 6);
  int ig = wid & 255;
  int sp = wid >> 8;
  int i  = ig * 64 + lane;

  // wave-uniform batch from the wave's first i (boundaries at 4096/8192/12288)
  int batch = (4 * (ig * 64)) / 16383;     // 0..3
  int js = batch * 4096;
  int je = (batch == 3) ? 16383 : js + 4096;

  const float4* xg4 = (const float4*)xg;
  float4 xi[12];
#pragma unroll
  for (int q = 0; q < 12; ++q) xi[q] = xg4[(size_t)i * 13 + q];

  unsigned long long q9[9];
#pragma unroll
  for (int k = 0; k < 9; ++k) q9[k] = ~0ull;

  for (int j = js + sp; j < je; j += S) {
    int ju = __builtin_amdgcn_readfirstlane(j);
    const float4* rp = (const float4*)(xg + (size_t)ju * 52);
    float4 r[13];
#pragma unroll
    for (int q = 0; q < 13; ++q) r[q] = rp[q];
    float ax = 0.f, ay = 0.f, az = 0.f, aw = 0.f;
#pragma unroll
    for (int q = 0; q < 12; ++q) {
      ax += r[q].x * xi[q].x;
      ay += r[q].y * xi[q].y;
      az += r[q].z * xi[q].z;
      aw += r[q].w * xi[q].w;
    }
    // ranking key: sq[j] - 2*dot (sq[i] per-row constant, dropped; order preserved)
    float dist = r[12].x - 2.0f * ((ax + ay) + (az + aw));
    unsigned k32 = __float_as_uint(dist);
    k32 = ((int)k32 >= 0) ? (k32 | 0x80000000u) : ~k32;  // sortable-uint map
    unsigned long long key = ((unsigned long long)k32 << 14) | (unsigned)ju;
    if (key < q9[8]) {
      unsigned long long cu = key;
#pragma unroll
      for (int k = 0; k < 9; ++k) {
        bool lt = cu < q9[k];
        unsigned long long mn = lt ? cu : q9[k];
        cu    = lt ? q9[k] : cu;
        q9[k] = mn;
      }
    }
  }

  // coalesced partial store: part[(k*S + sp)*NN + i]
#pragma unroll
  for (int k = 0; k < 9; ++k) part[(size_t)(k * S + sp) * NN + i] = q9[k];
}

// ---------- kernel 3: merge S sorted partial lists -> nbr, deg ----------
__global__ __launch_bounds__(256) void merge_kernel(const unsigned long long* __restrict__ part,
                                                    int S,
                                                    int* __restrict__ nbr,
                                                    int* __restrict__ deg) {
  int i = blockIdx.x * 256 + threadIdx.x;
  unsigned long long q9[9];
#pragma unroll
  for (int k = 0; k < 9; ++k) q9[k] = ~0ull;
  for (int s = 0; s < S; ++s) {
    for (int k = 0; k < 9; ++k) {
      unsigned long long key = part[(size_t)(k * S + s) * NN + i];
      if (key >= q9[8]) break;   // list k-sorted ascending
      unsigned long long cu = key;
#pragma unroll
      for (int m = 0; m < 9; ++m) {
        bool lt = cu < q9[m];
        unsigned long long mn = lt ? cu : q9[m];
        cu    = lt ? q9[m] : cu;
        q9[m] = mn;
      }
    }
  }
  int outi[9];
#pragma unroll
  for (int k = 0; k < 9; ++k) outi[k] = (int)(q9[k] & 0x3FFFull);
  // node 16383 sits alone in "batch 4": top_k over one valid entry + (-inf) ties
  // -> neighbors {16383, 0,1,...,7} (lowest-index tie-break). Matters for deg[0..7].
  if (i == NN - 1) {
    outi[0] = NN - 1;
#pragma unroll
    for (int k = 1; k < 9; ++k) outi[k] = k - 1;
  }
#pragma unroll
  for (int k = 0; k < 9; ++k) {
    nbr[i * 9 + k] = outi[k];
    atomicAdd(&deg[outi[k]], 1);
  }
}

// ---------- kernel 4: dinv ----------
__global__ __launch_bounds__(256) void dinv_kernel(const int* __restrict__ deg,
                                                   float* __restrict__ dinv) {
  int i = blockIdx.x * 256 + threadIdx.x;
  int d = deg[i];
  dinv[i] = d > 0 ? 1.0f / sqrtf((float)d) : 0.0f;
}

// ---------- kernel 5: tx1 gather + out = relu(xf@W0 + tx1@W1 + b) ----------
__global__ __launch_bounds__(256) void out_kernel(const float* __restrict__ xg,
                                                  const int* __restrict__ nbr,
                                                  const float* __restrict__ dinv,
                                                  const float* __restrict__ W0,
                                                  const float* __restrict__ W1,
                                                  const float* __restrict__ bias,
                                                  float* __restrict__ out) {
  __shared__ float w0s[48 * 48], w1s[48 * 48], bsh[48];
  __shared__ __align__(16) float xr[64 * 48];
  __shared__ float tx[64 * 48];
  __shared__ float wd[64][9];
  __shared__ int   jn[64][9];
  __shared__ float din[64];
  int tid = threadIdx.x;
  int r0  = blockIdx.x * 64;

  for (int p = tid; p < 2304; p += 256) { w0s[p] = W0[p]; w1s[p] = W1[p]; }
  if (tid < 48) bsh[tid] = bias[tid];
  if (tid < 64) din[tid] = dinv[r0 + tid];
  const float4* xg4 = (const float4*)xg;
  float4* xr4 = (float4*)xr;
  for (int p = tid; p < 768; p += 256) {
    int r = p / 12, q = p - r * 12;
    xr4[r * 12 + q] = xg4[(r0 + r) * 13 + q];
  }
  for (int p = tid; p < 576; p += 256) {
    int r = p / 9, k = p - r * 9;
    int j = nbr[(r0 + r) * 9 + k];
    jn[r][k] = j;
    wd[r][k] = dinv[j];
  }
  __syncthreads();

  for (int p = tid; p < 3072; p += 256) {
    int r = p / 48, ch = p - r * 48;
    float s = 0.f;
#pragma unroll
    for (int k = 0; k < 9; ++k) s += wd[r][k] * xg[jn[r][k] * 52 + ch];
    tx[r * 48 + ch] = -din[r] * s;
  }
  __syncthreads();

  for (int p = tid; p < 3072; p += 256) {
    int r = p / 48, o = p - r * 48;
    float acc = bsh[o];
#pragma unroll
    for (int cc = 0; cc < 48; ++cc)
      acc += xr[r * 48 + cc] * w0s[cc * 48 + o] + tx[r * 48 + cc] * w1s[cc * 48 + o];
    out[(r0 + r) * 48 + o] = fmaxf(acc, 0.f);
  }
}

extern "C" void kernel_launch(void* const* d_in, const int* in_sizes, int n_in,
                              void* d_out, int out_size, void* d_ws, size_t ws_size,
                              hipStream_t stream) {
  const float* x  = (const float*)d_in[0];
  const float* W0 = (const float*)d_in[1];
  const float* W1 = (const float*)d_in[2];
  const float* b  = (const float*)d_in[3];
  float* out = (float*)d_out;
  char* ws = (char*)d_ws;
  float* xg   = (float*)(ws);                 // 16384*52*4 = 3,407,872 B
  int*   nbr  = (int*)(ws + 3407872);         // 16384*9*4  =   589,824 B
  int*   deg  = (int*)(ws + 3997696);         //               65,536 B
  float* dinv = (float*)(ws + 4063232);       //               65,536 B
  unsigned long long* part = (unsigned long long*)(ws + 4128768);
  const size_t base = 4128768;
  const size_t per_split = (size_t)9 * NN * 8;   // 1,179,648 B per split
  int S = (ws_size >= base + 16 * per_split) ? 16
        : (ws_size >= base + 8 * per_split)  ? 8
                                             : 4;

  hipMemsetAsync(deg, 0, NN * sizeof(int), stream);
  prep_kernel<<<256, 256, 0, stream>>>(x, xg);
  knn_kernel<<<64 * S, 256, 0, stream>>>(xg, part, S);
  merge_kernel<<<64, 256, 0, stream>>>(part, S, nbr, deg);
  dinv_kernel<<<64, 256, 0, stream>>>(deg, dinv);
  out_kernel<<<256, 256, 0, stream>>>(xg, nbr, dinv, W0, W1, b, out);
}

// Round 4
// 335.023 us; speedup vs baseline: 2.5692x; 1.4364x over previous
//
#include <hip/hip_runtime.h>

#define NN 16384   // total nodes (4*64*64)
#define CC 48      // channels
// xg layout: per node, 52 floats = 48 features + [sq, 0, 0, 0]  (13 float4, 16B aligned)

// ---------- kernel 1: [B,C,H,W] -> xg[N][52] (features + squared-norm) ----------
__global__ __launch_bounds__(256) void prep_kernel(const float* __restrict__ x,
                                                   float* __restrict__ xg) {
  __shared__ float tile[48][65];   // +1 pad
  __shared__ float sqcol[64];
  int tid = threadIdx.x;
  int b   = blockIdx.x >> 6;          // batch image 0..3
  int hw0 = (blockIdx.x & 63) << 6;   // 64-wide hw tile
#pragma unroll
  for (int p = 0; p < 12; ++p) {
    int it = tid + p * 256;
    int r = it >> 6, col = it & 63;
    tile[r][col] = x[(b * 48 + r) * 4096 + hw0 + col];
  }
  __syncthreads();
  if (tid < 64) {
    float s = 0.f;
#pragma unroll
    for (int r = 0; r < 48; ++r) { float v = tile[r][tid]; s += v * v; }
    sqcol[tid] = s;
  }
  __syncthreads();
  float4* xg4 = (float4*)xg;
#pragma unroll
  for (int p = 0; p < 4; ++p) {
    int it = tid + p * 256;
    if (it < 832) {
      int col = it / 13;
      int q   = it - col * 13;
      float4 v;
      if (q < 12) {
        v.x = tile[q * 4 + 0][col]; v.y = tile[q * 4 + 1][col];
        v.z = tile[q * 4 + 2][col]; v.w = tile[q * 4 + 3][col];
      } else {
        v.x = sqcol[col]; v.y = 0.f; v.z = 0.f; v.w = 0.f;
      }
      xg4[(b * 4096 + hw0 + col) * 13 + q] = v;
    }
  }
}

// ---------- kernel 2: fused distance + partial top-9 ----------
// Block = 256 thr (4 waves) owns 256 consecutive i (lane-per-i); all 4 waves
// share ONE j-stream (js+sp, step S). Rows staged block-cooperatively into a
// double-buffered LDS tile (8 rows/iter) via coalesced float4 VMEM; each wave
// then reads rows with uniform-address ds_read_b128 broadcasts (conflict-free)
// into VGPRs for all-VGPR v_fmac_f32.
// Top-9 keys as EXACT integers in f64: key = sortable_u32(dist)*16384 + j
// (46 bits, exact). Sorted-insert via fmin/fmax f64 (2 inst/slot vs 5 for u64);
// ordering + lower-index tie-break identical to the u64 key.
// Node 16383 (alone in "batch 4"): excluded as candidate via ju==16383 guard;
// its query lane computes garbage, fully overridden in merge_kernel.
__global__ __launch_bounds__(256, 3) void knn_kernel(const float* __restrict__ xg,
                                                     double* __restrict__ part,
                                                     int S) {
  __shared__ float buf[2][8][52];
  int tid  = threadIdx.x;
  int lane = tid & 63;
  int wv   = tid >> 6;
  int ig   = blockIdx.x & 63;
  int sp   = blockIdx.x >> 6;
  int i    = ig * 256 + wv * 64 + lane;
  int batch = ig >> 4;                 // 16 ig-blocks per batch image
  int js = batch * 4096;
  int n  = 4096 / S;                   // candidates per lane-stream
  int T  = n >> 3;                     // macro-iters (8 rows each)

  const float4* xg4 = (const float4*)xg;
  float4 xi[12];
#pragma unroll
  for (int q = 0; q < 12; ++q) xi[q] = xg4[(size_t)i * 13 + q];

  double q9[9];
#pragma unroll
  for (int k = 0; k < 9; ++k) q9[k] = __builtin_inf();

  // staging map: thread p<104 loads float4 q of row r (r=p/13, q=p%13)
  int p  = tid;
  int r  = p / 13;
  int qq = p - r * 13;
  bool st = (p < 104);
  const float4* sptr = xg4 + ((size_t)(js + sp + S * r) * 13 + qq);
  int stride = 104 * S;                // 8*S rows * 13 float4 per macro-iter
  float4 pf = st ? sptr[0] : make_float4(0.f, 0.f, 0.f, 0.f);
  sptr += stride;

  for (int t = 0; t < T; ++t) {
    int cur = t & 1;
    if (st) *(float4*)(&buf[cur][r][qq * 4]) = pf;
    if (st && (t + 1 < T)) pf = sptr[0];
    sptr += stride;
    __syncthreads();
    int jbase = js + sp + S * (t * 8);
#pragma unroll
    for (int rr = 0; rr < 8; ++rr) {
      const float* rowp = buf[cur][rr];
      int ju = jbase + S * rr;
      float ax = 0.f, ay = 0.f, az = 0.f, aw = 0.f;
#pragma unroll
      for (int q = 0; q < 12; ++q) {
        float4 rv = *(const float4*)(rowp + 4 * q);
        ax += rv.x * xi[q].x;
        ay += rv.y * xi[q].y;
        az += rv.z * xi[q].z;
        aw += rv.w * xi[q].w;
      }
      float sqj = rowp[48];
      float dist = fmaf(-2.0f, (ax + ay) + (az + aw), sqj);
      unsigned k32 = __float_as_uint(dist);
      k32 = ((int)k32 >= 0) ? (k32 | 0x80000000u) : ~k32;  // sortable-uint map
      if (ju == NN - 1) k32 = 0xFFFFFFFFu;  // exclude node 16383 as candidate
      double key = (double)k32 * 16384.0 + (double)ju;     // exact 46-bit int
      if (key < q9[8]) {
        double cu = key;
#pragma unroll
        for (int k = 0; k < 9; ++k) {
          double mn = fmin(cu, q9[k]);
          cu        = fmax(cu, q9[k]);
          q9[k]     = mn;
        }
      }
    }
  }

  // coalesced partial store: part[(k*S + sp)*NN + i]
#pragma unroll
  for (int k = 0; k < 9; ++k) part[(size_t)(k * S + sp) * NN + i] = q9[k];
}

// ---------- kernel 3: merge S sorted partial lists -> nbr, deg ----------
__global__ __launch_bounds__(256) void merge_kernel(const double* __restrict__ part,
                                                    int S,
                                                    int* __restrict__ nbr,
                                                    int* __restrict__ deg) {
  int i = blockIdx.x * 256 + threadIdx.x;
  double q9[9];
#pragma unroll
  for (int k = 0; k < 9; ++k) q9[k] = __builtin_inf();
  for (int s = 0; s < S; ++s) {
    for (int k = 0; k < 9; ++k) {
      double key = part[(size_t)(k * S + s) * NN + i];
      if (key >= q9[8]) break;   // list k-sorted ascending
      double cu = key;
#pragma unroll
      for (int m = 0; m < 9; ++m) {
        double mn = fmin(cu, q9[m]);
        cu        = fmax(cu, q9[m]);
        q9[m]     = mn;
      }
    }
  }
  int outi[9];
#pragma unroll
  for (int k = 0; k < 9; ++k) {
    double d  = q9[k];
    double hi = floor(d * 6.103515625e-05);   // d * 2^-14, exact
    outi[k] = (int)(d - hi * 16384.0);        // exact index recovery
  }
  // node 16383 sits alone in "batch 4": top_k over one valid entry + (-inf) ties
  // -> neighbors {16383, 0,1,...,7} (lowest-index tie-break). Matters for deg[0..7].
  if (i == NN - 1) {
    outi[0] = NN - 1;
#pragma unroll
    for (int k = 1; k < 9; ++k) outi[k] = k - 1;
  }
#pragma unroll
  for (int k = 0; k < 9; ++k) {
    nbr[i * 9 + k] = outi[k];
    atomicAdd(&deg[outi[k]], 1);
  }
}

// ---------- kernel 4: tx1 gather + out = relu(xf@W0 + tx1@W1 + b) ----------
// dinv fused: computed on the fly from deg (saves a kernel launch).
__global__ __launch_bounds__(256) void out_kernel(const float* __restrict__ xg,
                                                  const int* __restrict__ nbr,
                                                  const int* __restrict__ deg,
                                                  const float* __restrict__ W0,
                                                  const float* __restrict__ W1,
                                                  const float* __restrict__ bias,
                                                  float* __restrict__ out) {
  __shared__ float w0s[48 * 48], w1s[48 * 48], bsh[48];
  __shared__ __align__(16) float xr[64 * 48];
  __shared__ float tx[64 * 48];
  __shared__ float wd[64][9];
  __shared__ int   jn[64][9];
  __shared__ float din[64];
  int tid = threadIdx.x;
  int r0  = blockIdx.x * 64;

  for (int p = tid; p < 2304; p += 256) { w0s[p] = W0[p]; w1s[p] = W1[p]; }
  if (tid < 48) bsh[tid] = bias[tid];
  if (tid < 64) {
    int d = deg[r0 + tid];
    din[tid] = d > 0 ? rsqrtf((float)d) : 0.0f;
  }
  const float4* xg4 = (const float4*)xg;
  float4* xr4 = (float4*)xr;
  for (int p = tid; p < 768; p += 256) {
    int r = p / 12, q = p - r * 12;
    xr4[r * 12 + q] = xg4[(r0 + r) * 13 + q];
  }
  for (int p = tid; p < 576; p += 256) {
    int r = p / 9, k = p - r * 9;
    int j = nbr[(r0 + r) * 9 + k];
    jn[r][k] = j;
    int d = deg[j];
    wd[r][k] = d > 0 ? rsqrtf((float)d) : 0.0f;
  }
  __syncthreads();

  for (int p = tid; p < 3072; p += 256) {
    int r = p / 48, ch = p - r * 48;
    float s = 0.f;
#pragma unroll
    for (int k = 0; k < 9; ++k) s += wd[r][k] * xg[jn[r][k] * 52 + ch];
    tx[r * 48 + ch] = -din[r] * s;
  }
  __syncthreads();

  for (int p = tid; p < 3072; p += 256) {
    int r = p / 48, o = p - r * 48;
    float acc = bsh[o];
#pragma unroll
    for (int cc = 0; cc < 48; ++cc)
      acc += xr[r * 48 + cc] * w0s[cc * 48 + o] + tx[r * 48 + cc] * w1s[cc * 48 + o];
    out[(r0 + r) * 48 + o] = fmaxf(acc, 0.f);
  }
}

extern "C" void kernel_launch(void* const* d_in, const int* in_sizes, int n_in,
                              void* d_out, int out_size, void* d_ws, size_t ws_size,
                              hipStream_t stream) {
  const float* x  = (const float*)d_in[0];
  const float* W0 = (const float*)d_in[1];
  const float* W1 = (const float*)d_in[2];
  const float* b  = (const float*)d_in[3];
  float* out = (float*)d_out;
  char* ws = (char*)d_ws;
  float* xg   = (float*)(ws);                 // 16384*52*4 = 3,407,872 B
  int*   nbr  = (int*)(ws + 3407872);         // 16384*9*4  =   589,824 B
  int*   deg  = (int*)(ws + 3997696);         //               65,536 B
  double* part = (double*)(ws + 4128768);     // S*9*NN*8 B
  const size_t base = 4128768;
  const size_t per_split = (size_t)9 * NN * 8;   // 1,179,648 B per split
  int S = (ws_size >= base + 16 * per_split) ? 16
        : (ws_size >= base + 8 * per_split)  ? 8
                                             : 4;

  hipMemsetAsync(deg, 0, NN * sizeof(int), stream);
  prep_kernel<<<256, 256, 0, stream>>>(x, xg);
  knn_kernel<<<64 * S, 256, 0, stream>>>(xg, part, S);
  merge_kernel<<<64, 256, 0, stream>>>(part, S, nbr, deg);
  out_kernel<<<256, 256, 0, stream>>>(xg, nbr, deg, W0, W1, b, out);
}

// Round 5
// 331.019 us; speedup vs baseline: 2.6003x; 1.0121x over previous
//
#include <hip/hip_runtime.h>

#define NN 16384   // total nodes (4*64*64)
#define CC 48      // channels
#define CAP 16     // per-lane deferred-candidate buffer slots
// xg layout: per node, 52 floats = 48 features + [sq, 0, 0, 0]  (13 float4, 16B aligned)

// ---------- kernel 1: [B,C,H,W] -> xg[N][52] (features + squared-norm) ----------
// Also zeroes deg[] (folds the memset dispatch).
__global__ __launch_bounds__(256) void prep_kernel(const float* __restrict__ x,
                                                   float* __restrict__ xg,
                                                   int* __restrict__ deg) {
  __shared__ float tile[48][65];   // +1 pad
  __shared__ float sqcol[64];
  int tid = threadIdx.x;
  int b   = blockIdx.x >> 6;          // batch image 0..3
  int hw0 = (blockIdx.x & 63) << 6;   // 64-wide hw tile
  if (tid < 64) deg[blockIdx.x * 64 + tid] = 0;
#pragma unroll
  for (int p = 0; p < 12; ++p) {
    int it = tid + p * 256;
    int r = it >> 6, col = it & 63;
    tile[r][col] = x[(b * 48 + r) * 4096 + hw0 + col];
  }
  __syncthreads();
  if (tid < 64) {
    float s = 0.f;
#pragma unroll
    for (int r = 0; r < 48; ++r) { float v = tile[r][tid]; s += v * v; }
    sqcol[tid] = s;
  }
  __syncthreads();
  float4* xg4 = (float4*)xg;
#pragma unroll
  for (int p = 0; p < 4; ++p) {
    int it = tid + p * 256;
    if (it < 832) {
      int col = it / 13;
      int q   = it - col * 13;
      float4 v;
      if (q < 12) {
        v.x = tile[q * 4 + 0][col]; v.y = tile[q * 4 + 1][col];
        v.z = tile[q * 4 + 2][col]; v.w = tile[q * 4 + 3][col];
      } else {
        v.x = sqcol[col]; v.y = 0.f; v.z = 0.f; v.w = 0.f;
      }
      xg4[(b * 4096 + hw0 + col) * 13 + q] = v;
    }
  }
}

// ---------- kernel 2: fused distance + deferred top-9 ----------
// Block = 4 waves owns 256 consecutive i (lane-per-i); one shared j-stream
// (js+sp, step S), rows double-buffered in LDS, read via uniform-address
// ds_read_b128 broadcasts.
// Selection is DECOUPLED: hot path keeps only th32 (u32 dist part of q9[8]).
// Candidates with k32 <= th32 (superset of exact accept) are packed as exact
// 46-bit integer keys in f64 (key = k32*2^14 + j) and pushed to a per-lane LDS
// buffer. When any lane's buffer can't absorb another 8-candidate tile
// (__any(cnt > CAP-8)), all lanes batch-merge their buffers into the sorted
// top-9 q9 (fmin/fmax f64 chain) and th32 tightens. q9 is COLD -> may live in
// AGPRs cheaply; xi stays hot in arch VGPRs.
// Node 16383 (alone in "batch 4"): k32 forced to 0xFFFFFFFF; >=255 real
// candidates per split evict it; its own query lane is overridden in merge.
__global__ __launch_bounds__(256, 4) void knn_kernel(const float* __restrict__ xg,
                                                     double* __restrict__ part,
                                                     int S) {
  __shared__ float buf[2][8][52];
  __shared__ double bq[CAP][256];   // [slot][tid] = 32 KB
  int tid  = threadIdx.x;
  int lane = tid & 63;
  int wv   = tid >> 6;
  int ig   = blockIdx.x & 63;
  int sp   = blockIdx.x >> 6;
  int i    = ig * 256 + wv * 64 + lane;
  int batch = ig >> 4;                 // 16 ig-blocks per batch image
  int js = batch * 4096;
  int T  = (4096 / S) >> 3;            // macro-tiles of 8 rows

  const float4* xg4 = (const float4*)xg;
  float4 xi[12];
#pragma unroll
  for (int q = 0; q < 12; ++q) xi[q] = xg4[(size_t)i * 13 + q];

  double q9[9];
#pragma unroll
  for (int k = 0; k < 9; ++k) q9[k] = __builtin_inf();
  unsigned th32 = 0xFFFFFFFFu;
  int cnt = 0;

  // staging map: thread p<104 loads float4 qq of row r (r=p/13, qq=p%13)
  int p  = tid;
  int r  = p / 13;
  int qq = p - r * 13;
  bool st = (p < 104);
  const float4* sptr = xg4 + ((size_t)(js + sp + S * r) * 13 + qq);
  int stride = 104 * S;                // 8*S rows * 13 float4 per macro-tile
  float4 pf = st ? sptr[0] : make_float4(0.f, 0.f, 0.f, 0.f);
  sptr += stride;

  for (int t = 0; t < T; ++t) {
    int cur = t & 1;
    if (st) *(float4*)(&buf[cur][r][qq * 4]) = pf;
    if (st && (t + 1 < T)) pf = sptr[0];
    sptr += stride;
    __syncthreads();
    int jbase = js + sp + S * (t * 8);
#pragma unroll
    for (int rr = 0; rr < 8; ++rr) {
      const float* rowp = buf[cur][rr];
      float ax = 0.f, ay = 0.f, az = 0.f, aw = 0.f;
#pragma unroll
      for (int q = 0; q < 12; ++q) {
        float4 rv = *(const float4*)(rowp + 4 * q);
        ax += rv.x * xi[q].x;
        ay += rv.y * xi[q].y;
        az += rv.z * xi[q].z;
        aw += rv.w * xi[q].w;
      }
      float dist = fmaf(-2.0f, (ax + ay) + (az + aw), rowp[48]);
      unsigned k32 = __float_as_uint(dist);
      k32 = ((int)k32 >= 0) ? (k32 | 0x80000000u) : ~k32;  // sortable-uint map
      int ju = jbase + S * rr;
      if (ju == NN - 1) k32 = 0xFFFFFFFFu;  // exclude node 16383 as candidate
      if (k32 <= th32) {
        unsigned long long uk = ((unsigned long long)k32 << 14) | (unsigned)ju;
        bq[cnt][tid] = (double)uk;          // exact 46-bit integer in f64
        cnt++;
      }
    }
    // merge when the next tile (<=8 accepts) could overflow anyone's buffer
    if (__any(cnt > CAP - 8)) {
#pragma unroll 1
      for (int m = 0; m < CAP; ++m) {
        bool act = m < cnt;
        if (!__any(act)) break;
        double key = act ? bq[m][tid] : __builtin_inf();
        if (key < q9[8]) {
          double cu = key;
#pragma unroll
          for (int k = 0; k < 9; ++k) {
            double mn = fmin(cu, q9[k]);
            cu        = fmax(cu, q9[k]);
            q9[k]     = mn;
          }
        }
      }
      cnt = 0;
      th32 = (q9[8] > 7.2e13) ? 0xFFFFFFFFu
                              : (unsigned)(q9[8] * 6.103515625e-05);  // *2^-14 exact
    }
  }
  // final flush
#pragma unroll 1
  for (int m = 0; m < CAP; ++m) {
    bool act = m < cnt;
    if (!__any(act)) break;
    double key = act ? bq[m][tid] : __builtin_inf();
    if (key < q9[8]) {
      double cu = key;
#pragma unroll
      for (int k = 0; k < 9; ++k) {
        double mn = fmin(cu, q9[k]);
        cu        = fmax(cu, q9[k]);
        q9[k]     = mn;
      }
    }
  }

  // coalesced partial store: part[(k*S + sp)*NN + i]
#pragma unroll
  for (int k = 0; k < 9; ++k) part[(size_t)(k * S + sp) * NN + i] = q9[k];
}

// ---------- kernel 3: merge S sorted partial lists -> nbr, deg ----------
__global__ __launch_bounds__(64) void merge_kernel(const double* __restrict__ part,
                                                   int S,
                                                   int* __restrict__ nbr,
                                                   int* __restrict__ deg) {
  int i = blockIdx.x * 64 + threadIdx.x;
  double q9[9];
#pragma unroll
  for (int k = 0; k < 9; ++k) q9[k] = __builtin_inf();
  for (int s = 0; s < S; ++s) {
    for (int k = 0; k < 9; ++k) {
      double key = part[(size_t)(k * S + s) * NN + i];
      if (key >= q9[8]) break;   // list k-sorted ascending
      double cu = key;
#pragma unroll
      for (int m = 0; m < 9; ++m) {
        double mn = fmin(cu, q9[m]);
        cu        = fmax(cu, q9[m]);
        q9[m]     = mn;
      }
    }
  }
  int outi[9];
#pragma unroll
  for (int k = 0; k < 9; ++k) {
    double d  = q9[k];
    double hi = floor(d * 6.103515625e-05);   // d * 2^-14, exact
    outi[k] = (int)(d - hi * 16384.0);        // exact index recovery
  }
  // node 16383 sits alone in "batch 4": top_k over one valid entry + (-inf) ties
  // -> neighbors {16383, 0,1,...,7} (lowest-index tie-break). Matters for deg[0..7].
  if (i == NN - 1) {
    outi[0] = NN - 1;
#pragma unroll
    for (int k = 1; k < 9; ++k) outi[k] = k - 1;
  }
#pragma unroll
  for (int k = 0; k < 9; ++k) {
    nbr[i * 9 + k] = outi[k];
    atomicAdd(&deg[outi[k]], 1);
  }
}

// ---------- kernel 4: tx1 gather + out = relu(xf@W0 + tx1@W1 + b) ----------
// dinv fused: computed on the fly from deg.
__global__ __launch_bounds__(256) void out_kernel(const float* __restrict__ xg,
                                                  const int* __restrict__ nbr,
                                                  const int* __restrict__ deg,
                                                  const float* __restrict__ W0,
                                                  const float* __restrict__ W1,
                                                  const float* __restrict__ bias,
                                                  float* __restrict__ out) {
  __shared__ float w0s[48 * 48], w1s[48 * 48], bsh[48];
  __shared__ __align__(16) float xr[64 * 48];
  __shared__ float tx[64 * 48];
  __shared__ float wd[64][9];
  __shared__ int   jn[64][9];
  __shared__ float din[64];
  int tid = threadIdx.x;
  int r0  = blockIdx.x * 64;

  for (int p = tid; p < 2304; p += 256) { w0s[p] = W0[p]; w1s[p] = W1[p]; }
  if (tid < 48) bsh[tid] = bias[tid];
  if (tid < 64) {
    int d = deg[r0 + tid];
    din[tid] = d > 0 ? rsqrtf((float)d) : 0.0f;
  }
  const float4* xg4 = (const float4*)xg;
  float4* xr4 = (float4*)xr;
  for (int p = tid; p < 768; p += 256) {
    int r = p / 12, q = p - r * 12;
    xr4[r * 12 + q] = xg4[(r0 + r) * 13 + q];
  }
  for (int p = tid; p < 576; p += 256) {
    int r = p / 9, k = p - r * 9;
    int j = nbr[(r0 + r) * 9 + k];
    jn[r][k] = j;
    int d = deg[j];
    wd[r][k] = d > 0 ? rsqrtf((float)d) : 0.0f;
  }
  __syncthreads();

  for (int p = tid; p < 3072; p += 256) {
    int r = p / 48, ch = p - r * 48;
    float s = 0.f;
#pragma unroll
    for (int k = 0; k < 9; ++k) s += wd[r][k] * xg[jn[r][k] * 52 + ch];
    tx[r * 48 + ch] = -din[r] * s;
  }
  __syncthreads();

  for (int p = tid; p < 3072; p += 256) {
    int r = p / 48, o = p - r * 48;
    float acc = bsh[o];
#pragma unroll
    for (int cc = 0; cc < 48; ++cc)
      acc += xr[r * 48 + cc] * w0s[cc * 48 + o] + tx[r * 48 + cc] * w1s[cc * 48 + o];
    out[(r0 + r) * 48 + o] = fmaxf(acc, 0.f);
  }
}

extern "C" void kernel_launch(void* const* d_in, const int* in_sizes, int n_in,
                              void* d_out, int out_size, void* d_ws, size_t ws_size,
                              hipStream_t stream) {
  const float* x  = (const float*)d_in[0];
  const float* W0 = (const float*)d_in[1];
  const float* W1 = (const float*)d_in[2];
  const float* b  = (const float*)d_in[3];
  float* out = (float*)d_out;
  char* ws = (char*)d_ws;
  float* xg   = (float*)(ws);                 // 16384*52*4 = 3,407,872 B
  int*   nbr  = (int*)(ws + 3407872);         // 16384*9*4  =   589,824 B
  int*   deg  = (int*)(ws + 3997696);         //               65,536 B
  double* part = (double*)(ws + 4128768);     // S*9*NN*8 B
  const size_t base = 4128768;
  const size_t per_split = (size_t)9 * NN * 8;   // 1,179,648 B per split
  int S = (ws_size >= base + 16 * per_split) ? 16
        : (ws_size >= base + 8 * per_split)  ? 8
                                             : 4;

  prep_kernel<<<256, 256, 0, stream>>>(x, xg, deg);
  knn_kernel<<<64 * S, 256, 0, stream>>>(xg, part, S);
  merge_kernel<<<256, 64, 0, stream>>>(part, S, nbr, deg);
  out_kernel<<<256, 256, 0, stream>>>(xg, nbr, deg, W0, W1, b, out);
}

// Round 6
// 264.529 us; speedup vs baseline: 3.2538x; 1.2513x over previous
//
#include <hip/hip_runtime.h>

#define NN 16384   // total nodes (4*64*64)
#define CC 48      // channels
#define SPL 4      // j-stream splits
#define CAP 64     // per-query LDS deferred-buffer slots

typedef __attribute__((ext_vector_type(8))) short bf16x8;
typedef __attribute__((ext_vector_type(4))) float f32x4;

__device__ __forceinline__ unsigned short f2bf(float f) {
  unsigned u = __float_as_uint(f);
  unsigned r = ((u >> 16) & 1u) + 0x7fffu;   // RNE
  return (unsigned short)((u + r) >> 16);
}
__device__ __forceinline__ float bf2f(unsigned short h) {
  return __uint_as_float(((unsigned)h) << 16);
}

// ---------- kernel 1: [B,C,H,W] -> xg[N][52] fp32, xh/xl[N][64] bf16 split, sqv[N] ----------
// Also zeroes deg[].
__global__ __launch_bounds__(256) void prep_kernel(const float* __restrict__ x,
                                                   float* __restrict__ xg,
                                                   unsigned short* __restrict__ xh,
                                                   unsigned short* __restrict__ xl,
                                                   float* __restrict__ sqv,
                                                   int* __restrict__ deg) {
  __shared__ float tile[48][65];   // +1 pad
  __shared__ float sqcol[64];
  int tid = threadIdx.x;
  int b   = blockIdx.x >> 6;          // batch image 0..3
  int hw0 = (blockIdx.x & 63) << 6;   // 64-wide hw tile
  if (tid < 64) deg[blockIdx.x * 64 + tid] = 0;
#pragma unroll
  for (int p = 0; p < 12; ++p) {
    int it = tid + p * 256;
    int r = it >> 6, col = it & 63;
    tile[r][col] = x[(b * 48 + r) * 4096 + hw0 + col];
  }
  __syncthreads();
  if (tid < 64) {
    float s = 0.f;
#pragma unroll
    for (int r = 0; r < 48; ++r) { float v = tile[r][tid]; s += v * v; }
    sqcol[tid] = s;
    sqv[b * 4096 + hw0 + tid] = s;
  }
  __syncthreads();
  float4* xg4 = (float4*)xg;
#pragma unroll
  for (int p = 0; p < 4; ++p) {
    int it = tid + p * 256;
    if (it < 832) {
      int col = it / 13;
      int q   = it - col * 13;
      float4 v;
      if (q < 12) {
        v.x = tile[q * 4 + 0][col]; v.y = tile[q * 4 + 1][col];
        v.z = tile[q * 4 + 2][col]; v.w = tile[q * 4 + 3][col];
      } else {
        v.x = sqcol[col]; v.y = 0.f; v.z = 0.f; v.w = 0.f;
      }
      xg4[(b * 4096 + hw0 + col) * 13 + q] = v;
    }
  }
  // bf16 hi/lo split, channels padded 48..63 with zeros
#pragma unroll
  for (int p = 0; p < 16; ++p) {
    int it = tid + p * 256;          // 4096 = 64 nodes x 64 ch
    int col = it >> 6, ch = it & 63;
    float v = (ch < 48) ? tile[ch][col] : 0.f;
    unsigned short h = f2bf(v);
    unsigned short l = f2bf(v - bf2f(h));
    size_t o = (size_t)(b * 4096 + hw0 + col) * 64 + ch;
    xh[o] = h;
    xl[o] = l;
  }
}

// ---------- kernel 2: MFMA distance + deferred top-9 ----------
// Wave owns 16 queries (A-frags resident); streams 1024 candidates (split sp)
// as 64 tiles of 16. dot = hi.hi' + hi.lo' + lo.hi' via 6 chained
// mfma_f32_16x16x32_bf16 (K=48 zero-padded to 64). C/D: col=lane&15,
// row=quad*4+reg (m89-verified). A: [m=lane&15][k=quad*8+e] (m120); B mirrored.
// Epilogue: key = (sortable_u32(sq_j - 2 dot) << 14) | j; accept if
// k32 <= th32[reg] (stale-threshold superset); push to per-query LDS buffer
// (ds_add_rtn slot). Wave-local flush when any slot >= CAP-16 (<=16 pushes
// per query per tile -> no overflow): owner lanes (<16) merge into
// register-resident sorted top-9, thresholds rebroadcast via __shfl.
// Node 16383 (alone in "batch 4") excluded via k32=max; its own query row is
// overridden in merge_kernel.
__global__ __launch_bounds__(256, 4) void knn_kernel(const unsigned short* __restrict__ xh,
                                                     const unsigned short* __restrict__ xl,
                                                     const float* __restrict__ sqv,
                                                     unsigned long long* __restrict__ part) {
  __shared__ unsigned long long bufq[4][16][CAP];   // 32 KB
  __shared__ int cnt[4][16];
  int tid = threadIdx.x, wv = tid >> 6, lane = tid & 63;
  int wid = blockIdx.x * 4 + wv;
  int qt = wid & 1023, sp = wid >> 10;
  int col = lane & 15, quad = lane >> 4;
  int batch = qt >> 8;
  int js = batch * 4096 + sp * 1024;

  if (lane < 16) cnt[wv][lane] = 0;
  __threadfence_block();

  // resident A-frags for this wave's 16 queries
  int qnode = qt * 16 + col;
  bf16x8 ah0 = *(const bf16x8*)(xh + (size_t)qnode * 64 + 0  + quad * 8);
  bf16x8 ah1 = *(const bf16x8*)(xh + (size_t)qnode * 64 + 32 + quad * 8);
  bf16x8 al0 = *(const bf16x8*)(xl + (size_t)qnode * 64 + 0  + quad * 8);
  bf16x8 al1 = *(const bf16x8*)(xl + (size_t)qnode * 64 + 32 + quad * 8);

  unsigned long long q9[9];
#pragma unroll
  for (int k = 0; k < 9; ++k) q9[k] = ~0ull;
  unsigned th32[4] = {0xFFFFFFFFu, 0xFFFFFFFFu, 0xFFFFFFFFu, 0xFFFFFFFFu};

  // prefetch tile 0
  int jn = js + col;
  bf16x8 bh0 = *(const bf16x8*)(xh + (size_t)jn * 64 + 0  + quad * 8);
  bf16x8 bh1 = *(const bf16x8*)(xh + (size_t)jn * 64 + 32 + quad * 8);
  bf16x8 bl0 = *(const bf16x8*)(xl + (size_t)jn * 64 + 0  + quad * 8);
  bf16x8 bl1 = *(const bf16x8*)(xl + (size_t)jn * 64 + 32 + quad * 8);
  float sqj = sqv[jn];

  for (int t = 0; t < 64; ++t) {
    bf16x8 cb0 = bh0, cb1 = bh1, cb2 = bl0, cb3 = bl1;
    float csq = sqj;
    int jc = js + t * 16 + col;
    int tn = (t < 63) ? t + 1 : 63;
    int jn2 = js + tn * 16 + col;
    bh0 = *(const bf16x8*)(xh + (size_t)jn2 * 64 + 0  + quad * 8);
    bh1 = *(const bf16x8*)(xh + (size_t)jn2 * 64 + 32 + quad * 8);
    bl0 = *(const bf16x8*)(xl + (size_t)jn2 * 64 + 0  + quad * 8);
    bl1 = *(const bf16x8*)(xl + (size_t)jn2 * 64 + 32 + quad * 8);
    sqj = sqv[jn2];

    f32x4 acc = {0.f, 0.f, 0.f, 0.f};
    acc = __builtin_amdgcn_mfma_f32_16x16x32_bf16(ah0, cb0, acc, 0, 0, 0);  // hi.hi k0-31
    acc = __builtin_amdgcn_mfma_f32_16x16x32_bf16(ah1, cb1, acc, 0, 0, 0);  // hi.hi k32-63
    acc = __builtin_amdgcn_mfma_f32_16x16x32_bf16(ah0, cb2, acc, 0, 0, 0);  // hi.lo
    acc = __builtin_amdgcn_mfma_f32_16x16x32_bf16(ah1, cb3, acc, 0, 0, 0);
    acc = __builtin_amdgcn_mfma_f32_16x16x32_bf16(al0, cb0, acc, 0, 0, 0);  // lo.hi
    acc = __builtin_amdgcn_mfma_f32_16x16x32_bf16(al1, cb1, acc, 0, 0, 0);

    unsigned flag = 0;
    bool excl = (jc == NN - 1);
#pragma unroll
    for (int reg = 0; reg < 4; ++reg) {
      float d = fmaf(-2.f, acc[reg], csq);   // key: sq_j - 2 dot (sq_i dropped)
      unsigned k32 = __float_as_uint(d);
      k32 = ((int)k32 >= 0) ? (k32 | 0x80000000u) : ~k32;  // sortable map
      if (excl) k32 = 0xFFFFFFFFu;
      if (k32 <= th32[reg]) {
        unsigned long long key = ((unsigned long long)k32 << 14) | (unsigned)jc;
        int r = quad * 4 + reg;
        int slot = atomicAdd(&cnt[wv][r], 1);
        bufq[wv][r][slot] = key;
        if (slot >= CAP - 16) flag = 1;
      }
    }
    if (__any(flag)) {
      __threadfence_block();
      if (lane < 16) {
        int n = cnt[wv][lane];
        for (int m = 0; m < n; ++m) {
          unsigned long long key = bufq[wv][lane][m];
          if (key < q9[8]) {
            unsigned long long cu = key;
#pragma unroll
            for (int kk = 0; kk < 9; ++kk) {
              bool lt = cu < q9[kk];
              unsigned long long mn = lt ? cu : q9[kk];
              cu     = lt ? q9[kk] : cu;
              q9[kk] = mn;
            }
          }
        }
        cnt[wv][lane] = 0;
      }
      __threadfence_block();
#pragma unroll
      for (int reg = 0; reg < 4; ++reg)
        th32[reg] = (unsigned)(__shfl(q9[8], quad * 4 + reg, 64) >> 14);
    }
  }

  // final flush + store
  __threadfence_block();
  if (lane < 16) {
    int n = cnt[wv][lane];
    for (int m = 0; m < n; ++m) {
      unsigned long long key = bufq[wv][lane][m];
      if (key < q9[8]) {
        unsigned long long cu = key;
#pragma unroll
        for (int kk = 0; kk < 9; ++kk) {
          bool lt = cu < q9[kk];
          unsigned long long mn = lt ? cu : q9[kk];
          cu     = lt ? q9[kk] : cu;
          q9[kk] = mn;
        }
      }
    }
    int i = qt * 16 + lane;
#pragma unroll
    for (int k = 0; k < 9; ++k) part[(size_t)(k * SPL + sp) * NN + i] = q9[k];
  }
}

// ---------- kernel 3: merge SPL sorted partial lists -> nbr, deg ----------
__global__ __launch_bounds__(64) void merge_kernel(const unsigned long long* __restrict__ part,
                                                   int* __restrict__ nbr,
                                                   int* __restrict__ deg) {
  int i = blockIdx.x * 64 + threadIdx.x;
  unsigned long long q9[9];
#pragma unroll
  for (int k = 0; k < 9; ++k) q9[k] = ~0ull;
  for (int s = 0; s < SPL; ++s) {
    for (int k = 0; k < 9; ++k) {
      unsigned long long key = part[(size_t)(k * SPL + s) * NN + i];
      if (key >= q9[8]) break;   // list k-sorted ascending
      unsigned long long cu = key;
#pragma unroll
      for (int m = 0; m < 9; ++m) {
        bool lt = cu < q9[m];
        unsigned long long mn = lt ? cu : q9[m];
        cu    = lt ? q9[m] : cu;
        q9[m] = mn;
      }
    }
  }
  int outi[9];
#pragma unroll
  for (int k = 0; k < 9; ++k) outi[k] = (int)(q9[k] & 0x3FFFull);
  // node 16383 sits alone in "batch 4": top_k over one valid entry + (-inf) ties
  // -> neighbors {16383, 0,1,...,7} (lowest-index tie-break). Matters for deg[0..7].
  if (i == NN - 1) {
    outi[0] = NN - 1;
#pragma unroll
    for (int k = 1; k < 9; ++k) outi[k] = k - 1;
  }
#pragma unroll
  for (int k = 0; k < 9; ++k) {
    nbr[i * 9 + k] = outi[k];
    atomicAdd(&deg[outi[k]], 1);
  }
}

// ---------- kernel 4: tx1 gather + out = relu(xf@W0 + tx1@W1 + b) ----------
__global__ __launch_bounds__(256) void out_kernel(const float* __restrict__ xg,
                                                  const int* __restrict__ nbr,
                                                  const int* __restrict__ deg,
                                                  const float* __restrict__ W0,
                                                  const float* __restrict__ W1,
                                                  const float* __restrict__ bias,
                                                  float* __restrict__ out) {
  __shared__ float w0s[48 * 48], w1s[48 * 48], bsh[48];
  __shared__ __align__(16) float xr[64 * 48];
  __shared__ float tx[64 * 48];
  __shared__ float wd[64][9];
  __shared__ int   jn[64][9];
  __shared__ float din[64];
  int tid = threadIdx.x;
  int r0  = blockIdx.x * 64;

  for (int p = tid; p < 2304; p += 256) { w0s[p] = W0[p]; w1s[p] = W1[p]; }
  if (tid < 48) bsh[tid] = bias[tid];
  if (tid < 64) {
    int d = deg[r0 + tid];
    din[tid] = d > 0 ? rsqrtf((float)d) : 0.0f;
  }
  const float4* xg4 = (const float4*)xg;
  float4* xr4 = (float4*)xr;
  for (int p = tid; p < 768; p += 256) {
    int r = p / 12, q = p - r * 12;
    xr4[r * 12 + q] = xg4[(r0 + r) * 13 + q];
  }
  for (int p = tid; p < 576; p += 256) {
    int r = p / 9, k = p - r * 9;
    int j = nbr[(r0 + r) * 9 + k];
    jn[r][k] = j;
    int d = deg[j];
    wd[r][k] = d > 0 ? rsqrtf((float)d) : 0.0f;
  }
  __syncthreads();

  for (int p = tid; p < 3072; p += 256) {
    int r = p / 48, ch = p - r * 48;
    float s = 0.f;
#pragma unroll
    for (int k = 0; k < 9; ++k) s += wd[r][k] * xg[jn[r][k] * 52 + ch];
    tx[r * 48 + ch] = -din[r] * s;
  }
  __syncthreads();

  for (int p = tid; p < 3072; p += 256) {
    int r = p / 48, o = p - r * 48;
    float acc = bsh[o];
#pragma unroll
    for (int cc = 0; cc < 48; ++cc)
      acc += xr[r * 48 + cc] * w0s[cc * 48 + o] + tx[r * 48 + cc] * w1s[cc * 48 + o];
    out[(r0 + r) * 48 + o] = fmaxf(acc, 0.f);
  }
}

extern "C" void kernel_launch(void* const* d_in, const int* in_sizes, int n_in,
                              void* d_out, int out_size, void* d_ws, size_t ws_size,
                              hipStream_t stream) {
  const float* x  = (const float*)d_in[0];
  const float* W0 = (const float*)d_in[1];
  const float* W1 = (const float*)d_in[2];
  const float* b  = (const float*)d_in[3];
  float* out = (float*)d_out;
  char* ws = (char*)d_ws;
  float*          xg   = (float*)(ws);                       // 3,407,872 B
  unsigned short* xh   = (unsigned short*)(ws + 3407872);    // 2,097,152 B
  unsigned short* xl   = (unsigned short*)(ws + 5505024);    // 2,097,152 B
  float*          sqv  = (float*)(ws + 7602176);             //    65,536 B
  int*            nbr  = (int*)(ws + 7667712);               //   589,824 B
  int*            deg  = (int*)(ws + 8257536);               //    65,536 B
  unsigned long long* part = (unsigned long long*)(ws + 8323072);  // 4,718,592 B

  prep_kernel<<<256, 256, 0, stream>>>(x, xg, xh, xl, sqv, deg);
  knn_kernel<<<1024, 256, 0, stream>>>(xh, xl, sqv, part);
  merge_kernel<<<256, 64, 0, stream>>>(part, nbr, deg);
  out_kernel<<<256, 256, 0, stream>>>(xg, nbr, deg, W0, W1, b, out);
}

// Round 7
// 244.974 us; speedup vs baseline: 3.5136x; 1.0798x over previous
//
#include <hip/hip_runtime.h>

#define NN 16384   // total nodes (4*64*64)
#define CC 48      // channels
#define SPL 4      // j-stream splits
#define CAPQ 16    // per-lane deferred-buffer slots

typedef __attribute__((ext_vector_type(8))) short bf16x8;
typedef __attribute__((ext_vector_type(4))) float f32x4;

__device__ __forceinline__ unsigned short f2bf(float f) {
  unsigned u = __float_as_uint(f);
  unsigned r = ((u >> 16) & 1u) + 0x7fffu;   // RNE
  return (unsigned short)((u + r) >> 16);
}
__device__ __forceinline__ float bf2f(unsigned short h) {
  return __uint_as_float(((unsigned)h) << 16);
}

// ---------- kernel 1: [B,C,H,W] -> xg[N][52] fp32, xh/xl[N][64] bf16 split, sqv[N] ----------
// Also zeroes deg[]; sqv[16383] = +inf (excludes the lone "batch 4" node as a
// candidate for batch-3 queries at zero hot-loop cost: dist = inf, never ranked).
__global__ __launch_bounds__(256) void prep_kernel(const float* __restrict__ x,
                                                   float* __restrict__ xg,
                                                   unsigned short* __restrict__ xh,
                                                   unsigned short* __restrict__ xl,
                                                   float* __restrict__ sqv,
                                                   int* __restrict__ deg) {
  __shared__ float tile[48][65];   // +1 pad
  __shared__ float sqcol[64];
  int tid = threadIdx.x;
  int b   = blockIdx.x >> 6;          // batch image 0..3
  int hw0 = (blockIdx.x & 63) << 6;   // 64-wide hw tile
  if (tid < 64) deg[blockIdx.x * 64 + tid] = 0;
#pragma unroll
  for (int p = 0; p < 12; ++p) {
    int it = tid + p * 256;
    int r = it >> 6, col = it & 63;
    tile[r][col] = x[(b * 48 + r) * 4096 + hw0 + col];
  }
  __syncthreads();
  if (tid < 64) {
    float s = 0.f;
#pragma unroll
    for (int r = 0; r < 48; ++r) { float v = tile[r][tid]; s += v * v; }
    sqcol[tid] = s;
    int node = b * 4096 + hw0 + tid;
    sqv[node] = (node == NN - 1) ? __builtin_inff() : s;
  }
  __syncthreads();
  float4* xg4 = (float4*)xg;
#pragma unroll
  for (int p = 0; p < 4; ++p) {
    int it = tid + p * 256;
    if (it < 832) {
      int col = it / 13;
      int q   = it - col * 13;
      float4 v;
      if (q < 12) {
        v.x = tile[q * 4 + 0][col]; v.y = tile[q * 4 + 1][col];
        v.z = tile[q * 4 + 2][col]; v.w = tile[q * 4 + 3][col];
      } else {
        v.x = sqcol[col]; v.y = 0.f; v.z = 0.f; v.w = 0.f;
      }
      xg4[(b * 4096 + hw0 + col) * 13 + q] = v;
    }
  }
  // bf16 hi/lo split, channels padded 48..63 with zeros
#pragma unroll
  for (int p = 0; p < 16; ++p) {
    int it = tid + p * 256;          // 4096 = 64 nodes x 64 ch
    int col = it >> 6, ch = it & 63;
    float v = (ch < 48) ? tile[ch][col] : 0.f;
    unsigned short h = f2bf(v);
    unsigned short l = f2bf(v - bf2f(h));
    size_t o = (size_t)(b * 4096 + hw0 + col) * 64 + ch;
    xh[o] = h;
    xl[o] = l;
  }
}

// ---------- kernel 2: MFMA distance + per-lane private top-9 ----------
// Roles: A = candidates (streamed), B = queries (resident). C/D row = A's m =
// candidate quad*4+reg, col = B's n = query lane&15 (m89/m120 layouts). So each
// lane owns ONE query and sees 4 candidates/tile -> selection is lane-private:
//  - accept test vs per-lane stale threshold th32 (= own q9[8]>>14, superset)
//  - accepted keys (u64: sortable_u32(dist)<<14 | j) pushed to a PRIVATE LDS
//    buffer (plain ds_write, register cnt, NO atomics)
//  - flush when __any(cnt > CAPQ-4): all 64 lanes batch-scan their own
//    fixed-bound buffers into register-sorted top-9 (parallel, unrollable)
// dot = hi.hi' + hi.lo' + lo.hi' via 6 chained mfma_f32_16x16x32_bf16 (K=48
// padded to 64). sq_j for rows quad*4..+3 = one broadcast float4.
// End: 4 quad-partials per query merged in-wave (lanes<16), stored per split.
__global__ __launch_bounds__(256, 4) void knn_kernel(const unsigned short* __restrict__ xh,
                                                     const unsigned short* __restrict__ xl,
                                                     const float* __restrict__ sqv,
                                                     unsigned long long* __restrict__ part) {
  __shared__ unsigned long long bufq[4][64][CAPQ + 1];   // 34.8 KB, stride 17 u64
  int tid = threadIdx.x, wv = tid >> 6, lane = tid & 63;
  int wid = blockIdx.x * 4 + wv;
  int qt = wid & 1023, sp = wid >> 10;
  int col = lane & 15, quad = lane >> 4;
  int batch = qt >> 8;
  int js = batch * 4096 + sp * 1024;

  unsigned long long* myb = bufq[wv][lane];

  // resident B-frags (queries)
  int qnode = qt * 16 + col;
  bf16x8 bh0 = *(const bf16x8*)(xh + (size_t)qnode * 64 + quad * 8);
  bf16x8 bh1 = *(const bf16x8*)(xh + (size_t)qnode * 64 + 32 + quad * 8);
  bf16x8 bl0 = *(const bf16x8*)(xl + (size_t)qnode * 64 + quad * 8);
  bf16x8 bl1 = *(const bf16x8*)(xl + (size_t)qnode * 64 + 32 + quad * 8);

  unsigned long long q9[9];
#pragma unroll
  for (int k = 0; k < 9; ++k) q9[k] = ~0ull;
  unsigned th32 = 0xFFFFFFFFu;
  int cnt = 0;

  auto flush = [&]() {
#pragma unroll
    for (int m = 0; m < CAPQ; ++m) {
      unsigned long long key = myb[m];
      if (m < cnt && key < q9[8]) {
        unsigned long long cu = key;
#pragma unroll
        for (int kk = 0; kk < 9; ++kk) {
          bool lt = cu < q9[kk];
          unsigned long long mn = lt ? cu : q9[kk];
          cu     = lt ? q9[kk] : cu;
          q9[kk] = mn;
        }
      }
    }
    cnt = 0;
    th32 = (unsigned)(q9[8] >> 14);
  };

  // prefetch tile 0: A-frags (candidate node js + col) + sq float4
  const unsigned short* pah = xh + ((size_t)(js + col) * 64 + quad * 8);
  const unsigned short* pal = xl + ((size_t)(js + col) * 64 + quad * 8);
  const float*          psq = sqv + (js + quad * 4);
  bf16x8 nh0 = *(const bf16x8*)(pah);
  bf16x8 nh1 = *(const bf16x8*)(pah + 32);
  bf16x8 nl0 = *(const bf16x8*)(pal);
  bf16x8 nl1 = *(const bf16x8*)(pal + 32);
  float4 nsq = *(const float4*)(psq);

  for (int t = 0; t < 64; ++t) {
    bf16x8 ch0 = nh0, ch1 = nh1, cl0 = nl0, cl1 = nl1;
    float4 csq = nsq;
    int adv = (t < 63) ? 1024 : 0;       // 16 nodes * 64 ch
    pah += adv; pal += adv;
    nh0 = *(const bf16x8*)(pah);
    nh1 = *(const bf16x8*)(pah + 32);
    nl0 = *(const bf16x8*)(pal);
    nl1 = *(const bf16x8*)(pal + 32);
    psq += (t < 63) ? 16 : 0;
    nsq = *(const float4*)(psq);

    f32x4 acc = {0.f, 0.f, 0.f, 0.f};
    acc = __builtin_amdgcn_mfma_f32_16x16x32_bf16(ch0, bh0, acc, 0, 0, 0);  // hi.hi k0-31
    acc = __builtin_amdgcn_mfma_f32_16x16x32_bf16(ch1, bh1, acc, 0, 0, 0);  // hi.hi k32-63
    acc = __builtin_amdgcn_mfma_f32_16x16x32_bf16(ch0, bl0, acc, 0, 0, 0);  // hi.lo
    acc = __builtin_amdgcn_mfma_f32_16x16x32_bf16(ch1, bl1, acc, 0, 0, 0);
    acc = __builtin_amdgcn_mfma_f32_16x16x32_bf16(cl0, bh0, acc, 0, 0, 0);  // lo.hi
    acc = __builtin_amdgcn_mfma_f32_16x16x32_bf16(cl1, bh1, acc, 0, 0, 0);

    int jrow = js + t * 16 + quad * 4;
#pragma unroll
    for (int reg = 0; reg < 4; ++reg) {
      float sq = (reg == 0) ? csq.x : (reg == 1) ? csq.y : (reg == 2) ? csq.z : csq.w;
      float d = fmaf(-2.f, acc[reg], sq);    // key: sq_j - 2 dot (sq_i dropped)
      unsigned k32 = __float_as_uint(d);
      k32 = ((int)k32 >= 0) ? (k32 | 0x80000000u) : ~k32;   // sortable map
      if (k32 <= th32) {
        unsigned long long key = ((unsigned long long)k32 << 14) | (unsigned)(jrow + reg);
        myb[cnt] = key;
        cnt++;
      }
    }
    if (__any(cnt > CAPQ - 4)) flush();
  }
  flush();

  // in-wave merge of the 4 quad-partials per query
#pragma unroll
  for (int k = 0; k < 9; ++k) myb[k] = q9[k];
  __threadfence_block();
  if (lane < 16) {
#pragma unroll
    for (int qd = 1; qd < 4; ++qd) {
      const unsigned long long* ob = bufq[wv][qd * 16 + lane];
      for (int k = 0; k < 9; ++k) {
        unsigned long long key = ob[k];
        if (key >= q9[8]) break;           // sorted ascending
        unsigned long long cu = key;
#pragma unroll
        for (int kk = 0; kk < 9; ++kk) {
          bool lt = cu < q9[kk];
          unsigned long long mn = lt ? cu : q9[kk];
          cu     = lt ? q9[kk] : cu;
          q9[kk] = mn;
        }
      }
    }
    int i = qt * 16 + lane;
#pragma unroll
    for (int k = 0; k < 9; ++k) part[(size_t)(k * SPL + sp) * NN + i] = q9[k];
  }
}

// ---------- kernel 3: merge SPL sorted partial lists -> nbr, deg ----------
__global__ __launch_bounds__(64) void merge_kernel(const unsigned long long* __restrict__ part,
                                                   int* __restrict__ nbr,
                                                   int* __restrict__ deg) {
  int i = blockIdx.x * 64 + threadIdx.x;
  unsigned long long q9[9];
#pragma unroll
  for (int k = 0; k < 9; ++k) q9[k] = ~0ull;
  for (int s = 0; s < SPL; ++s) {
    for (int k = 0; k < 9; ++k) {
      unsigned long long key = part[(size_t)(k * SPL + s) * NN + i];
      if (key >= q9[8]) break;   // list k-sorted ascending
      unsigned long long cu = key;
#pragma unroll
      for (int m = 0; m < 9; ++m) {
        bool lt = cu < q9[m];
        unsigned long long mn = lt ? cu : q9[m];
        cu    = lt ? q9[m] : cu;
        q9[m] = mn;
      }
    }
  }
  int outi[9];
#pragma unroll
  for (int k = 0; k < 9; ++k) outi[k] = (int)(q9[k] & 0x3FFFull);
  // node 16383 sits alone in "batch 4": top_k over one valid entry + (-inf) ties
  // -> neighbors {16383, 0,1,...,7} (lowest-index tie-break). Matters for deg[0..7].
  if (i == NN - 1) {
    outi[0] = NN - 1;
#pragma unroll
    for (int k = 1; k < 9; ++k) outi[k] = k - 1;
  }
#pragma unroll
  for (int k = 0; k < 9; ++k) {
    nbr[i * 9 + k] = outi[k];
    atomicAdd(&deg[outi[k]], 1);
  }
}

// ---------- kernel 4: tx1 gather + out = relu(xf@W0 + tx1@W1 + b) ----------
__global__ __launch_bounds__(256) void out_kernel(const float* __restrict__ xg,
                                                  const int* __restrict__ nbr,
                                                  const int* __restrict__ deg,
                                                  const float* __restrict__ W0,
                                                  const float* __restrict__ W1,
                                                  const float* __restrict__ bias,
                                                  float* __restrict__ out) {
  __shared__ float w0s[48 * 48], w1s[48 * 48], bsh[48];
  __shared__ __align__(16) float xr[64 * 48];
  __shared__ float tx[64 * 48];
  __shared__ float wd[64][9];
  __shared__ int   jn[64][9];
  __shared__ float din[64];
  int tid = threadIdx.x;
  int r0  = blockIdx.x * 64;

  for (int p = tid; p < 2304; p += 256) { w0s[p] = W0[p]; w1s[p] = W1[p]; }
  if (tid < 48) bsh[tid] = bias[tid];
  if (tid < 64) {
    int d = deg[r0 + tid];
    din[tid] = d > 0 ? rsqrtf((float)d) : 0.0f;
  }
  const float4* xg4 = (const float4*)xg;
  float4* xr4 = (float4*)xr;
  for (int p = tid; p < 768; p += 256) {
    int r = p / 12, q = p - r * 12;
    xr4[r * 12 + q] = xg4[(r0 + r) * 13 + q];
  }
  for (int p = tid; p < 576; p += 256) {
    int r = p / 9, k = p - r * 9;
    int j = nbr[(r0 + r) * 9 + k];
    jn[r][k] = j;
    int d = deg[j];
    wd[r][k] = d > 0 ? rsqrtf((float)d) : 0.0f;
  }
  __syncthreads();

  for (int p = tid; p < 3072; p += 256) {
    int r = p / 48, ch = p - r * 48;
    float s = 0.f;
#pragma unroll
    for (int k = 0; k < 9; ++k) s += wd[r][k] * xg[jn[r][k] * 52 + ch];
    tx[r * 48 + ch] = -din[r] * s;
  }
  __syncthreads();

  for (int p = tid; p < 3072; p += 256) {
    int r = p / 48, o = p - r * 48;
    float acc = bsh[o];
#pragma unroll
    for (int cc = 0; cc < 48; ++cc)
      acc += xr[r * 48 + cc] * w0s[cc * 48 + o] + tx[r * 48 + cc] * w1s[cc * 48 + o];
    out[(r0 + r) * 48 + o] = fmaxf(acc, 0.f);
  }
}

extern "C" void kernel_launch(void* const* d_in, const int* in_sizes, int n_in,
                              void* d_out, int out_size, void* d_ws, size_t ws_size,
                              hipStream_t stream) {
  const float* x  = (const float*)d_in[0];
  const float* W0 = (const float*)d_in[1];
  const float* W1 = (const float*)d_in[2];
  const float* b  = (const float*)d_in[3];
  float* out = (float*)d_out;
  char* ws = (char*)d_ws;
  float*          xg   = (float*)(ws);                       // 3,407,872 B
  unsigned short* xh   = (unsigned short*)(ws + 3407872);    // 2,097,152 B
  unsigned short* xl   = (unsigned short*)(ws + 5505024);    // 2,097,152 B
  float*          sqv  = (float*)(ws + 7602176);             //    65,536 B
  int*            nbr  = (int*)(ws + 7667712);               //   589,824 B
  int*            deg  = (int*)(ws + 8257536);               //    65,536 B
  unsigned long long* part = (unsigned long long*)(ws + 8323072);  // 4,718,592 B

  prep_kernel<<<256, 256, 0, stream>>>(x, xg, xh, xl, sqv, deg);
  knn_kernel<<<1024, 256, 0, stream>>>(xh, xl, sqv, part);
  merge_kernel<<<256, 64, 0, stream>>>(part, nbr, deg);
  out_kernel<<<256, 256, 0, stream>>>(xg, nbr, deg, W0, W1, b, out);
}